// Round 1
// baseline (1956.736 us; speedup 1.0000x reference)
//
#include <hip/hip_runtime.h>
#include <math.h>

#define CDIM 512
#define LV 196
#define BV 64
#define BT 32
#define NW 24
#define NKEEP 98
#define NNON 98      // LV - NKEEP
#define KEEPED 49
#define HID 102
#define LAMBDA_ 4.0f
#define LN_EPS_ 1e-5f

// ws layout (float offsets)
#define WS_CAPNORM 0
#define WS_CAPGLO  (WS_CAPNORM + BT*NW*CDIM)     // 393216
#define WS_IMGGLO  (WS_CAPGLO + BT*CDIM)         // +16384
#define WS_INVN    (WS_IMGGLO + BV*CDIM)         // +32768
#define WS_WLOG    (WS_INVN + BV*LV)             // +12544
#define WS_SCORE   (WS_WLOG + BV*LV*KEEPED)      // +614656
// total = 1470976 floats = 5.88 MB

// ---------------------------------------------------------------------------
// K1: cap_norm, cap_glo (blocks 0..31), img_glo (blocks 32..95). 256 thr.
// ---------------------------------------------------------------------------
__global__ __launch_bounds__(256) void k1_glo(const float* __restrict__ img,
                                              const float* __restrict__ cap,
                                              float* __restrict__ ws) {
  __shared__ float red[256];
  int b = blockIdx.x, tid = threadIdx.x;
  int c0 = tid, c1 = tid + 256;
  if (b < BT) {
    int t = b;
    float s0 = 0.f, s1 = 0.f;
    for (int w = 0; w < NW; ++w) {
      const float* p = cap + ((size_t)t * NW + w) * CDIM;
      float x0 = p[c0], x1 = p[c1];
      red[tid] = x0 * x0 + x1 * x1;
      __syncthreads();
      for (int off = 128; off > 0; off >>= 1) {
        if (tid < off) red[tid] += red[tid + off];
        __syncthreads();
      }
      float inv = 1.f / fmaxf(sqrtf(red[0]), 1e-12f);
      __syncthreads();
      float* q = ws + WS_CAPNORM + ((size_t)t * NW + w) * CDIM;
      q[c0] = x0 * inv; q[c1] = x1 * inv;
      s0 += x0; s1 += x1;
    }
    float g0 = s0 / (float)NW, g1 = s1 / (float)NW;
    red[tid] = g0 * g0 + g1 * g1;
    __syncthreads();
    for (int off = 128; off > 0; off >>= 1) {
      if (tid < off) red[tid] += red[tid + off];
      __syncthreads();
    }
    float inv = 1.f / fmaxf(sqrtf(red[0]), 1e-12f);
    float* q = ws + WS_CAPGLO + (size_t)t * CDIM;
    q[c0] = g0 * inv; q[c1] = g1 * inv;
  } else {
    int v = b - BT;
    float s0 = 0.f, s1 = 0.f;
    const float* base = img + (size_t)v * LV * CDIM;
    for (int l = 0; l < LV; ++l) { s0 += base[l * CDIM + c0]; s1 += base[l * CDIM + c1]; }
    float g0 = s0 / (float)LV, g1 = s1 / (float)LV;
    red[tid] = g0 * g0 + g1 * g1;
    __syncthreads();
    for (int off = 128; off > 0; off >>= 1) {
      if (tid < off) red[tid] += red[tid + off];
      __syncthreads();
    }
    float inv = 1.f / fmaxf(sqrtf(red[0]), 1e-12f);
    float* q = ws + WS_IMGGLO + (size_t)v * CDIM;
    q[c0] = g0 * inv; q[c1] = g1 * inv;
  }
}

// ---------------------------------------------------------------------------
// K2: per img token: inv_norm, LN, MLP(gelu) -> wlog (49 logits/token).
// grid (64, 25), 256 thr, 8 tokens per block. W1 tiled through LDS.
// ---------------------------------------------------------------------------
#define TOK 8
__global__ __launch_bounds__(256) void k2_token(
    const float* __restrict__ img, const float* __restrict__ gamma,
    const float* __restrict__ beta, const float* __restrict__ W1,
    const float* __restrict__ b1, const float* __restrict__ W2,
    const float* __restrict__ b2, float* __restrict__ ws) {
  __shared__ float raw[TOK * CDIM];      // 16 KB
  __shared__ float xn[TOK * CDIM];       // 16 KB
  __shared__ float w1t[64 * HID];        // 25.5 KB
  __shared__ float hbuf[TOK * HID];      // 3.2 KB
  __shared__ float st_mean[TOK], st_rstd[TOK], st_invn[TOK];

  int v = blockIdx.x;
  int l0 = blockIdx.y * TOK;
  int tid = threadIdx.x;
  int nval = LV - l0; if (nval > TOK) nval = TOK; if (nval < 0) nval = 0;
  int wv = tid >> 6, lane = tid & 63;

  for (int i = tid; i < TOK * CDIM; i += 256) {
    int tok = i >> 9;
    raw[i] = (tok < nval) ? img[((size_t)v * LV + l0 + tok) * CDIM + (i & (CDIM - 1))] : 0.f;
  }
  __syncthreads();
  for (int tok = wv * 2; tok < wv * 2 + 2; ++tok) {
    float s = 0.f, sq = 0.f;
    #pragma unroll
    for (int j = 0; j < 8; ++j) { float x = raw[tok * CDIM + lane + 64 * j]; s += x; sq += x * x; }
    #pragma unroll
    for (int off = 32; off > 0; off >>= 1) { s += __shfl_xor(s, off, 64); sq += __shfl_xor(sq, off, 64); }
    if (lane == 0) {
      float mean = s / (float)CDIM;
      float var = sq / (float)CDIM - mean * mean;
      st_mean[tok] = mean;
      st_rstd[tok] = 1.f / sqrtf(var + LN_EPS_);
      st_invn[tok] = 1.f / fmaxf(sqrtf(sq), 1e-12f);
    }
  }
  __syncthreads();
  if (tid < nval) ws[WS_INVN + (size_t)v * LV + l0 + tid] = st_invn[tid];
  for (int i = tid; i < TOK * CDIM; i += 256) {
    int tok = i >> 9, c = i & (CDIM - 1);
    xn[i] = (raw[i] - st_mean[tok]) * st_rstd[tok] * gamma[c] + beta[c];
  }
  __syncthreads();

  // GEMM1: (8 tok x 512) @ (512 x 102), outputs 816, 4 per thread
  float acc1[4];
  int hh[4], tt[4]; bool av[4];
  #pragma unroll
  for (int s = 0; s < 4; ++s) {
    int oi = tid + 256 * s;
    av[s] = oi < TOK * HID;
    hh[s] = av[s] ? (oi % HID) : 0;
    tt[s] = av[s] ? (oi / HID) : 0;
    acc1[s] = av[s] ? b1[hh[s]] : 0.f;
  }
  for (int ct = 0; ct < 8; ++ct) {
    for (int i = tid; i < 64 * HID; i += 256) w1t[i] = W1[ct * 64 * HID + i];
    __syncthreads();
    for (int cc = 0; cc < 64; ++cc) {
      #pragma unroll
      for (int s = 0; s < 4; ++s)
        acc1[s] += xn[tt[s] * CDIM + ct * 64 + cc] * w1t[cc * HID + hh[s]];
    }
    __syncthreads();
  }
  #pragma unroll
  for (int s = 0; s < 4; ++s) {
    if (av[s]) {
      float x = acc1[s];
      float g = 0.5f * x * (1.f + erff(x * 0.70710678118654752f));
      hbuf[tid + 256 * s] = g;   // hbuf[tok*HID + h] == hbuf[oi]
    }
  }
  __syncthreads();

  // GEMM2: (8 tok x 102) @ (102 x 49) + b2 -> wlog
  #pragma unroll
  for (int s = 0; s < 2; ++s) {
    int oi = tid + 256 * s;
    if (oi < TOK * KEEPED) {
      int p = oi % KEEPED, tok = oi / KEEPED;
      float a = b2[p];
      for (int h2 = 0; h2 < HID; ++h2) a += hbuf[tok * HID + h2] * W2[h2 * KEEPED + p];
      if (tok < nval)
        ws[WS_WLOG + ((size_t)v * LV + l0 + tok) * KEEPED + p] = a;
    }
  }
}

// ---------------------------------------------------------------------------
// K3: scores. 33 queries (32 cap_glo + img_glo[v]) x tokens. grid (64,4).
// score[t,v,l] = (cap_glo[t].x + img_glo[v].x) * invn[v,l]
// ---------------------------------------------------------------------------
__global__ __launch_bounds__(256) void k3_score(const float* __restrict__ img,
                                                float* __restrict__ ws) {
  __shared__ float qt[33 * 64];     // 8.25 KB
  __shared__ float xt[64 * 65];     // 16.25 KB (padded)
  __shared__ float dself[64];
  int v = blockIdx.x;
  int t0 = blockIdx.y * 64;
  int tid = threadIdx.x;
  int tloc = tid & 63, qg = tid >> 6;
  float acc[9];
  #pragma unroll
  for (int i = 0; i < 9; ++i) acc[i] = 0.f;
  const float* capglo = ws + WS_CAPGLO;
  const float* imgglo = ws + WS_IMGGLO + (size_t)v * CDIM;

  for (int ct = 0; ct < 8; ++ct) {
    for (int i = tid; i < 33 * 64; i += 256) {
      int q = i >> 6, cc = i & 63;
      qt[i] = (q < 32) ? capglo[(size_t)q * CDIM + ct * 64 + cc] : imgglo[ct * 64 + cc];
    }
    for (int i = tid; i < 64 * 64; i += 256) {
      int tok = i >> 6, cc = i & 63;
      int l = t0 + tok;
      xt[tok * 65 + cc] = (l < LV) ? img[((size_t)v * LV + l) * CDIM + ct * 64 + cc] : 0.f;
    }
    __syncthreads();
    for (int cc = 0; cc < 64; ++cc) {
      float xv = xt[tloc * 65 + cc];
      #pragma unroll
      for (int qi = 0; qi < 9; ++qi) {
        int q = qg + 4 * qi;
        if (q < 33) acc[qi] += qt[q * 64 + cc] * xv;
      }
    }
    __syncthreads();
  }
  if (qg == 0) dself[tloc] = acc[8];  // q = 32
  __syncthreads();
  int l = t0 + tloc;
  if (l < LV) {
    float invn = ws[WS_INVN + (size_t)v * LV + l];
    float ds = dself[tloc];
    #pragma unroll
    for (int qi = 0; qi < 9; ++qi) {
      int q = qg + 4 * qi;
      if (q < 32) ws[WS_SCORE + ((size_t)q * BV + v) * LV + l] = (acc[qi] + ds) * invn;
    }
  }
}

// ---------------------------------------------------------------------------
// K4: per (t,v): rank/mask, extra token, pool softmax, aggr, l2norms,
// per-word attention + word_sim, mean. 2048 blocks x 512 thr.
// ---------------------------------------------------------------------------
__global__ __launch_bounds__(512) void k4_main(const float* __restrict__ img,
                                               const float* __restrict__ scale_p,
                                               const float* __restrict__ ws,
                                               float* __restrict__ out) {
  __shared__ float s_sc[LV];
  __shared__ int   s_kidx[NKEEP];
  __shared__ int   s_nidx[NNON];
  __shared__ int   s_cnt[2];
  __shared__ float s_wk[NNON];
  __shared__ float s_w[KEEPED * NKEEP];   // 19.2 KB, [p][k]
  __shared__ float s_sel[50 * CDIM];      // 100 KB, pools 0..48 aggr, 49 extra
  __shared__ float s_inv[50];
  __shared__ float s_red[128];
  __shared__ float s_tok[16 * CDIM];      // 32 KB staging for kept tokens

  int b = blockIdx.x;
  int v = b >> 5, t = b & 31;
  int tid = threadIdx.x;
  int wv = tid >> 6, lane = tid & 63;

  if (tid < 2) s_cnt[tid] = 0;
  if (tid < LV) s_sc[tid] = ws[WS_SCORE + ((size_t)t * BV + v) * LV + tid];
  __syncthreads();

  // --- rank & partition (stable argsort of -score semantics) ---
  if (tid < LV) {
    float my = s_sc[tid];
    int cnt = 0;
    for (int j = 0; j < LV; ++j) {
      float sj = s_sc[j];
      cnt += (sj > my) || (sj == my && j < tid);
    }
    bool keep = cnt < NKEEP;
    out[BV * BT + ((size_t)t * BV + v) * LV + tid] = keep ? 1.f : 0.f;
    if (keep) { int p = atomicAdd(&s_cnt[0], 1); s_kidx[p] = tid; }
    else      { int p = atomicAdd(&s_cnt[1], 1); s_nidx[p] = tid; }
  }
  __syncthreads();

  // --- softmax over non-kept scores ---
  if (tid < 128) s_red[tid] = (tid < NNON) ? s_sc[s_nidx[tid]] : -3.0e38f;
  __syncthreads();
  for (int off = 64; off > 0; off >>= 1) {
    if (tid < off) s_red[tid] = fmaxf(s_red[tid], s_red[tid + off]);
    __syncthreads();
  }
  float nm = s_red[0];
  __syncthreads();
  float e = 0.f;
  if (tid < NNON) e = expf(s_sc[s_nidx[tid]] - nm);
  if (tid < 128) s_red[tid] = e;
  __syncthreads();
  for (int off = 64; off > 0; off >>= 1) {
    if (tid < off) s_red[tid] += s_red[tid + off];
    __syncthreads();
  }
  float nS = s_red[0];
  __syncthreads();
  if (tid < NNON) s_wk[tid] = e / nS;
  __syncthreads();

  // --- extra token (pool 49): weighted sum of non-kept raw tokens ---
  {
    float acc = 0.f;
    const float* base = img + (size_t)v * LV * CDIM + tid;
    for (int k = 0; k < NNON; ++k) acc += s_wk[k] * base[(size_t)s_nidx[k] * CDIM];
    s_sel[49 * CDIM + tid] = acc;
  }

  // --- pool logits: gather wlog of kept tokens, * scale, softmax over k ---
  float scale_val = scale_p[0];
  for (int i = tid; i < KEEPED * NKEEP; i += 512) {
    int k = i / KEEPED, p = i - k * KEEPED;
    s_w[p * NKEEP + k] = ws[WS_WLOG + ((size_t)v * LV + s_kidx[k]) * KEEPED + p] * scale_val;
  }
  __syncthreads();
  if (tid < KEEPED) {
    int p = tid;
    float mm = -3e38f;
    for (int k = 0; k < NKEEP; ++k) mm = fmaxf(mm, s_w[p * NKEEP + k]);
    float ss = 0.f;
    for (int k = 0; k < NKEEP; ++k) { float ee = expf(s_w[p * NKEEP + k] - mm); s_w[p * NKEEP + k] = ee; ss += ee; }
    float rs = 1.f / ss;
    for (int k = 0; k < NKEEP; ++k) s_w[p * NKEEP + k] *= rs;
  }

  // --- aggr: wave wv owns pools {wv, wv+8, ...}; lanes own channels ---
  float acc[7][8];
  #pragma unroll
  for (int i = 0; i < 7; ++i)
    #pragma unroll
    for (int j = 0; j < 8; ++j) acc[i][j] = 0.f;

  for (int kt = 0; kt < NKEEP; kt += 16) {
    int kn = NKEEP - kt; if (kn > 16) kn = 16;
    __syncthreads();   // also covers s_w softmax completion on first iter
    for (int i = tid; i < kn * CDIM; i += 512) {
      int ko = i >> 9;
      s_tok[i] = img[((size_t)v * LV + s_kidx[kt + ko]) * CDIM + (i & (CDIM - 1))];
    }
    __syncthreads();
    for (int ko = 0; ko < kn; ++ko) {
      int k = kt + ko;
      float tv[8];
      #pragma unroll
      for (int j = 0; j < 8; ++j) tv[j] = s_tok[ko * CDIM + lane + 64 * j];
      #pragma unroll
      for (int i7 = 0; i7 < 7; ++i7) {
        int p = wv + 8 * i7;
        if (p < KEEPED) {
          float w = s_w[p * NKEEP + k];
          #pragma unroll
          for (int j = 0; j < 8; ++j) acc[i7][j] += w * tv[j];
        }
      }
    }
  }
  #pragma unroll
  for (int i7 = 0; i7 < 7; ++i7) {
    int p = wv + 8 * i7;
    if (p < KEEPED) {
      #pragma unroll
      for (int j = 0; j < 8; ++j) s_sel[p * CDIM + lane + 64 * j] = acc[i7][j];
    }
  }
  __syncthreads();

  // --- l2norm the 50 pools in place ---
  for (int p = wv; p < 50; p += 8) {
    float ss = 0.f;
    #pragma unroll
    for (int j = 0; j < 8; ++j) { float x = s_sel[p * CDIM + lane + 64 * j]; ss += x * x; }
    #pragma unroll
    for (int off = 32; off > 0; off >>= 1) ss += __shfl_xor(ss, off, 64);
    if (lane == 0) s_inv[p] = 1.f / fmaxf(sqrtf(ss), 1e-12f);
  }
  __syncthreads();
  for (int i = tid; i < 50 * CDIM; i += 512) s_sel[i] *= s_inv[i >> 9];
  __syncthreads();

  // --- per-word: sims -> softmax -> ctx -> l2norm -> word_sim; wave/word ---
  float wsum = 0.f;
  const float* capb = ws + WS_CAPNORM + (size_t)t * NW * CDIM;
  for (int w = wv; w < NW; w += 8) {
    float capv[8];
    #pragma unroll
    for (int j = 0; j < 8; ++j) capv[j] = capb[(size_t)w * CDIM + lane + 64 * j];
    float mylogit = -3e38f;
    float simmax = -3e38f;
    for (int p = 0; p < 50; ++p) {
      float s = 0.f;
      #pragma unroll
      for (int j = 0; j < 8; ++j) s += capv[j] * s_sel[p * CDIM + lane + 64 * j];
      #pragma unroll
      for (int off = 32; off > 0; off >>= 1) s += __shfl_xor(s, off, 64);
      float lg = LAMBDA_ * s;
      if (lane == p) mylogit = lg;
      simmax = fmaxf(simmax, lg);
    }
    float ee = (lane < 50) ? expf(mylogit - simmax) : 0.f;
    float d = ee;
    #pragma unroll
    for (int off = 32; off > 0; off >>= 1) d += __shfl_xor(d, off, 64);
    float attn = ee / d;
    float ctx[8];
    #pragma unroll
    for (int j = 0; j < 8; ++j) ctx[j] = 0.f;
    for (int p = 0; p < 50; ++p) {
      float a = __shfl(attn, p, 64);
      #pragma unroll
      for (int j = 0; j < 8; ++j) ctx[j] += a * s_sel[p * CDIM + lane + 64 * j];
    }
    float ss = 0.f, cw = 0.f;
    #pragma unroll
    for (int j = 0; j < 8; ++j) { ss += ctx[j] * ctx[j]; cw += ctx[j] * capv[j]; }
    #pragma unroll
    for (int off = 32; off > 0; off >>= 1) { ss += __shfl_xor(ss, off, 64); cw += __shfl_xor(cw, off, 64); }
    float invc = 1.f / fmaxf(sqrtf(ss), 1e-12f);
    wsum += cw * invc;
  }
  if (lane == 0) s_red[wv] = wsum;
  __syncthreads();
  if (tid == 0) {
    float s = 0.f;
    #pragma unroll
    for (int i = 0; i < 8; ++i) s += s_red[i];
    out[(size_t)v * BT + t] = s / (float)NW;   // improve_sims = sim.T
  }
}

// ---------------------------------------------------------------------------
extern "C" void kernel_launch(void* const* d_in, const int* in_sizes, int n_in,
                              void* d_out, int out_size, void* d_ws, size_t ws_size,
                              hipStream_t stream) {
  const float* img   = (const float*)d_in[0];
  const float* cap   = (const float*)d_in[1];
  // d_in[2] = cap_lens (unused by forward)
  const float* gamma = (const float*)d_in[3];
  const float* beta  = (const float*)d_in[4];
  const float* W1    = (const float*)d_in[5];
  const float* b1    = (const float*)d_in[6];
  const float* W2    = (const float*)d_in[7];
  const float* b2    = (const float*)d_in[8];
  const float* scale = (const float*)d_in[9];
  float* ws  = (float*)d_ws;
  float* out = (float*)d_out;

  k1_glo <<<dim3(BT + BV), dim3(256), 0, stream>>>(img, cap, ws);
  k2_token<<<dim3(BV, (LV + TOK - 1) / TOK), dim3(256), 0, stream>>>(img, gamma, beta, W1, b1, W2, b2, ws);
  k3_score<<<dim3(BV, 4), dim3(256), 0, stream>>>(img, ws);
  k4_main <<<dim3(BV * BT), dim3(512), 0, stream>>>(img, scale, ws, out);
}